// Round 5
// baseline (296.835 us; speedup 1.0000x reference)
//
#include <hip/hip_runtime.h>
#include <cstddef>
#include <cstdint>

// MinGRU: g/v/d = x@W{g,v,d}^T + b; xs = sigmoid(g)*tanh(v); a = 0.001+0.998*sigmoid(d)
// h_t = a_t*h_{t-1} + xs_t (causal scan over S). Output h [B,S,D] f32.
// B=4, S=4096, D=1024.
// R10: (a) counted-vmcnt double-buffered K-loop (T4): per tile
//      [vmcnt(7)][s_barrier][frags+MFMA w/ setprio][s_barrier][stage t+2];
//      raw s_barrier (no full drain) replaces __syncthreads; vmcnt never 0 in
//      the main loop. R9's syncthreads drained all 7 in-flight loads per tile
//      at 1 block/CU lockstep -> 84k cy/block vs ~40k ideal.
//      (b) scan2a folded into gemm epilogue: each block's 256 rows = exactly
//      one scan segment; fold 16 chunk (p,h) in LDS, write SP/SH directly
//      (same arithmetic order -> bitwise-identical). One fewer kernel.
//      (c) scan3 unroll 2->4.
// Pipeline: cvt -> gemm_fused -> scan2bc -> scan3.

typedef _Float16 f16;
typedef f16 f16x8 __attribute__((ext_vector_type(8)));
typedef float f32x4 __attribute__((ext_vector_type(4)));

#define S_LEN 4096
#define D_DIM 1024
#define B_DIM 4
#define M_TOT (B_DIM * S_LEN)  // 16384
#define N_TOT (3 * D_DIM)      // 3072
#define K_TOT D_DIM            // 1024

#define CLEN 16
#define CPB (S_LEN / CLEN)   // 256 chunks per batch
#define NCHUNK (B_DIM * CPB) // 1024 total chunks

#define SEG 16               // chunks per scan segment
#define NSEG (CPB / SEG)     // 16 segments per batch

// ---------------- merged f32 -> f16 convert: x, then interleaved weights ----------------
__device__ __forceinline__ void cvt8(const float* s, f16* d) {
  f32x4 a = *(const f32x4*)s;
  f32x4 b = *(const f32x4*)(s + 4);
  f16x8 o;
  o[0] = (f16)a[0]; o[1] = (f16)a[1]; o[2] = (f16)a[2]; o[3] = (f16)a[3];
  o[4] = (f16)b[0]; o[5] = (f16)b[1]; o[6] = (f16)b[2]; o[7] = (f16)b[3];
  *(f16x8*)d = o;
}

__global__ void cvt_all_kernel(const float* __restrict__ x, const float* __restrict__ w0,
                               const float* __restrict__ w1, const float* __restrict__ w2,
                               f16* __restrict__ Ah, f16* __restrict__ Bh) {
  int i = (blockIdx.x * 256 + threadIdx.x) * 8;
  if (i < M_TOT * K_TOT) {
    cvt8(x + i, Ah + i);
  } else {
    int w = i - M_TOT * K_TOT;   // 0 .. 3*2^20
    int row = w >> 10;           // interleaved dst row 0..3071
    int col = w & 1023;
    int srow = row / 3;
    int mat = row - srow * 3;
    const float* s = (mat == 0) ? w0 : (mat == 1) ? w1 : w2;
    cvt8(s + srow * 1024 + col, Bh + w);
  }
}

// ---------------- fused GEMM + activation + chunk/segment scan ----------------
#define BM 256
#define BN 192
#define BK 64
#define RAWP 200  // raw g/v/d tile pitch (halves), 128-row half-pass
#define XSP 72    // xs/a tile pitch (halves), padded vs bank conflicts

// LDS layout (halves):
//   As buf0 [0,16384)  buf1 [16384,32768)     (256 rows x 64)
//   Bs buf0 [32768,45056) buf1 [45056,57344)  (192 rows x 64)
// epilogue overlay: Raw [0,25600) = 128x200, xsL [25600,34816) = 128x72,
//   aL [34816,44032) = 128x72, segP/segH f32 [44032,48128) = 2x1024 f32.
#define AS_OFF 0
#define BS_OFF 32768
#define ABUF 16384
#define BBUF 12288
#define SMEM_H 57344  // 114688 B

__device__ __forceinline__ void gl_lds16(const void* g, void* l) {
  __builtin_amdgcn_global_load_lds((const __attribute__((address_space(1))) void*)g,
                                   (__attribute__((address_space(3))) void*)l, 16, 0, 0);
}

__device__ __forceinline__ void act(float g, float v, float d, f16& xh, f16& ah) {
  float sg = 1.f / (1.f + __expf(-g));
  float tv = 1.f - 2.f / (__expf(2.f * v) + 1.f);
  float sd = 1.f / (1.f + __expf(-d));
  xh = (f16)(sg * tv);
  ah = (f16)(0.001f + 0.998f * sd);
}

// grid = 1024 blocks (XCD-swizzled to 16 N x 64 M), 512 threads = 8 waves.
__global__ __launch_bounds__(512, 2) void gemm_fused_kernel(
    const f16* __restrict__ A, const f16* __restrict__ Bt,
    const float* __restrict__ bg, const float* __restrict__ bv,
    const float* __restrict__ bd,
    f16* __restrict__ xsA, f16* __restrict__ aA,
    float* __restrict__ P, float* __restrict__ H,
    float* __restrict__ SP, float* __restrict__ SH) {
  __shared__ __attribute__((aligned(16))) f16 smem[SMEM_H];
  const int tid = threadIdx.x;
  const int lane = tid & 63;
  const int wave = tid >> 6;

  // bijective XCD swizzle (nwg=1024 % 8 == 0): XCD c owns 128 consecutive
  // orig ids = 8 M-panels x 16 N-blocks, N-major -> A panel stays L2-hot.
  const int wg = blockIdx.x;
  const int orig = (wg & 7) * 128 + (wg >> 3);
  const int bx = orig & 15;   // N block 0..15
  const int by = orig >> 4;   // M block 0..63
  const int m0 = by * BM;
  const int bn0 = bx * BN;    // interleaved B row base (multiple of 3)

  // epilogue identifiers + bias loads issued EARLY (before the K-loop) so the
  // counted vmcnt in the loop only tracks the 7 staging loads per tile.
  const int d = tid & 63;        // channel within block (64 channels)
  const int cc = tid >> 6;       // chunk 0..7 within half-pass
  const int gd = (bx << 6) + d;  // global channel
  const float Bg = bg[gd], Bv = bv[gd], Bd_ = bd[gd];

  // ---- staging addressing: round = 512 threads x 16B = 64 rows x 8 slots ----
  // LDS dest is linear (gl_lds requirement); the global SOURCE k-slot is
  // pre-swizzled: LDS[row][s] holds global slot s ^ (row&7)  (involution).
  const int srow = tid >> 3;                        // 0..63
  const int sslot = (tid & 7) ^ (srow & 7);         // swizzled source slot
  const f16* aSrc = A + (size_t)(m0 + srow) * K_TOT + sslot * 8;
  const f16* bSrc = Bt + (size_t)(bn0 + srow) * K_TOT + sslot * 8;
  f16* aDst0 = smem + AS_OFF + tid * 8;             // + buf*ABUF + r*4096
  f16* bDst0 = smem + BS_OFF + tid * 8;             // + buf*BBUF + r*4096

  // ---- fragment addressing ----
  const int wm = (wave >> 1) * 64;  // 0/64/128/192
  const int wn = (wave & 1) * 96;   // 0/96
  const int lm = lane & 15;
  const int q = lane >> 4;
  // read-side swizzle: logical slot (kk*4+q) lives at (kk*4+q)^(row&7);
  // row&7 == lm&7 for all fragment rows (wm, i*16, j*16 are 0 mod 8).
  const int sw0 = ((0 * 4 + q) ^ (lm & 7)) * 8;
  const int sw1 = ((1 * 4 + q) ^ (lm & 7)) * 8;

  f32x4 acc[4][6] = {};

  // stage(tile, buf): 7 gl_lds16 per thread (4 A + 3 B).
  auto STAGE = [&](int tile, int buf) {
    const size_t k0 = (size_t)tile * BK;
#pragma unroll
    for (int r = 0; r < 4; ++r)
      gl_lds16(aSrc + (size_t)r * 64 * K_TOT + k0, aDst0 + buf * ABUF + r * 4096);
#pragma unroll
    for (int r = 0; r < 3; ++r)
      gl_lds16(bSrc + (size_t)r * 64 * K_TOT + k0, bDst0 + buf * BBUF + r * 4096);
  };

  // ---- prologue: both buffers in flight (14 outstanding loads/thread) ----
  STAGE(0, 0);
  STAGE(1, 1);

  // ---- main loop: counted vmcnt, raw barriers, never drain to 0 until tail.
  // iter t: [vmcnt(7): tile t landed (t+1's 7 still flying)] [barrier: all
  // waves' writes visible] [frags+MFMA on buf t&1] [barrier: everyone done
  // reading buf t&1] [stage t+2 into buf t&1].
  for (int t = 0; t < 16; ++t) {
    if (t < 15) {
      asm volatile("s_waitcnt vmcnt(7)" ::: "memory");
    } else {
      asm volatile("s_waitcnt vmcnt(0)" ::: "memory");
    }
    __builtin_amdgcn_s_barrier();
    __builtin_amdgcn_sched_barrier(0);  // no ds_read hoisting above the wait

    const f16* Acur = smem + AS_OFF + (t & 1) * ABUF;
    const f16* Bcur = smem + BS_OFF + (t & 1) * BBUF;
    __builtin_amdgcn_s_setprio(1);
#pragma unroll
    for (int kk = 0; kk < 2; ++kk) {
      const int sw = kk ? sw1 : sw0;
      f16x8 af[4], bf[6];
#pragma unroll
      for (int i = 0; i < 4; ++i)
        af[i] = *(const f16x8*)&Acur[(wm + i * 16 + lm) * BK + sw];
#pragma unroll
      for (int j = 0; j < 6; ++j)
        bf[j] = *(const f16x8*)&Bcur[(wn + j * 16 + lm) * BK + sw];
#pragma unroll
      for (int i = 0; i < 4; ++i)
#pragma unroll
        for (int j = 0; j < 6; ++j)
          acc[i][j] = __builtin_amdgcn_mfma_f32_16x16x32_f16(af[i], bf[j], acc[i][j], 0, 0, 0);
    }
    __builtin_amdgcn_s_setprio(0);
    __builtin_amdgcn_sched_barrier(0);  // no ds_read sinking below barrier A

    if (t < 14) {
      __builtin_amdgcn_s_barrier();  // all waves consumed buf t&1
      STAGE(t + 2, t & 1);
    }
  }
  __syncthreads();  // full drain before epilogue overlays the staging LDS

  // ---- epilogue: two 128-row half-passes through LDS overlay ----
  f16* Raw = smem;
  f16* xsL = smem + 25600;
  f16* aLs = smem + 34816;
  float* segP = (float*)(smem + 44032);  // [16][64] chunk p per (chunk, channel)
  float* segH = segP + 1024;             // [16][64] chunk h

#pragma unroll
  for (int half = 0; half < 2; ++half) {
    // 1) raw g/v/d -> LDS tile (f16, rounding contract shared with scan3)
    if ((wave >> 2) == half) {
      const int r0 = ((wave >> 1) & 1) * 64 + ((lane >> 4) << 2);  // row in half
      const int c0 = wn + (lane & 15);
#pragma unroll
      for (int i = 0; i < 4; ++i)
#pragma unroll
        for (int j = 0; j < 6; ++j)
#pragma unroll
          for (int r = 0; r < 4; ++r)
            Raw[(r0 + i * 16 + r) * RAWP + c0 + j * 16] = (f16)acc[i][j][r];
    }
    __syncthreads();

    // 2) activation + chunk-local scan; thread = (chunk cc, channel d)
    {
      float p = 1.f, h = 0.f;
#pragma unroll
      for (int i = 0; i < CLEN; ++i) {
        const int r = cc * CLEN + i;
        const f16* t3 = &Raw[r * RAWP + 3 * d];
        f16 xh, ah;
        act((float)t3[0] + Bg, (float)t3[1] + Bv, (float)t3[2] + Bd_, xh, ah);
        xsL[r * XSP + d] = xh;
        aLs[r * XSP + d] = ah;
        // use ROUNDED values so scan3 recomposition is exactly consistent
        float xf = (float)xh, af_ = (float)ah;
        h = af_ * h + xf;
        p *= af_;
      }
      const int gs = (m0 >> 4) + half * 8 + cc;  // global chunk index = m/16
      P[(size_t)gs * D_DIM + gd] = p;
      H[(size_t)gs * D_DIM + gd] = h;
      segP[(half * 8 + cc) * 64 + d] = p;
      segH[(half * 8 + cc) * 64 + d] = h;
    }
    __syncthreads();

    // 3) coalesced xs/a global stores (2 rounds x 64 rows x 64 cols)
#pragma unroll
    for (int rr = 0; rr < 2; ++rr) {
      const int row = rr * 64 + (tid >> 3);
      const int col = (tid & 7) * 8;
      const size_t gi = (size_t)(m0 + half * 128 + row) * D_DIM + (bx << 6) + col;
      *(f16x8*)(xsA + gi) = *(const f16x8*)&xsL[row * XSP + col];
      *(f16x8*)(aA + gi) = *(const f16x8*)&aLs[row * XSP + col];
    }
    __syncthreads();  // half=1 overwrites Raw/xsL/aLs
  }

  // ---- segment aggregate (replaces scan2a): block's 256 rows = segment `by`.
  // Same fold order/arithmetic as the old scan2a -> bitwise-identical SP/SH.
  if (tid < 64) {
    float ps = 1.f, hs = 0.f;
#pragma unroll
    for (int s = 0; s < 16; ++s) {
      const float pp = segP[s * 64 + tid];
      const float hh = segH[s * 64 + tid];
      hs = pp * hs + hh;
      ps *= pp;
    }
    const size_t so = (size_t)by * D_DIM + (bx << 6) + tid;
    SP[so] = ps;
    SH[so] = hs;
  }
}

// ---------------- scan pass 2: chain segment aggregates, expand to carries ----------------
__global__ void scan2bc_kernel(const float* __restrict__ P, const float* __restrict__ H,
                               const float* __restrict__ SP, const float* __restrict__ SH,
                               float* __restrict__ carry) {
  const int u = blockIdx.x * 256 + threadIdx.x;  // 0..65535
  const int d = u & 1023;
  const int s = (u >> 10) & (NSEG - 1);  // uniform within a 256-thread block
  const int b = u >> 14;
  float h = 0.f;
  for (int s2 = 0; s2 < s; ++s2) {
    const size_t off = (size_t)(b * NSEG + s2) * D_DIM + d;
    h = SP[off] * h + SH[off];
  }
  const int gs0 = b * CPB + s * SEG;
#pragma unroll 4
  for (int c = 0; c < SEG; ++c) {
    const size_t off = (size_t)(gs0 + c) * D_DIM + d;
    carry[off] = h;
    h = P[off] * h + H[off];
  }
}

// ---------------- scan pass 3: rescan with carry, write output ----------------
__global__ void scan3_kernel(const f16* __restrict__ xsA, const f16* __restrict__ aA,
                             const float* __restrict__ carry, float* __restrict__ out) {
  const int u = blockIdx.x * 256 + threadIdx.x;
  const int cg = u & 127;
  const int b = (u >> 7) & 3;
  const int ck = u >> 9;  // 0..255
  const int ch = cg * 8;
  const int base = (b * CPB + ck) * D_DIM + ch;
  float h[8];
  *(f32x4*)h = *(const f32x4*)(carry + base);
  *(f32x4*)(h + 4) = *(const f32x4*)(carry + base + 4);
  const int t0 = ck * CLEN;
#pragma unroll 4
  for (int t = t0; t < t0 + CLEN; ++t) {
    const size_t m = (size_t)b * S_LEN + t;
    f16x8 xs8 = *(const f16x8*)(xsA + m * D_DIM + ch);
    f16x8 a8 = *(const f16x8*)(aA + m * D_DIM + ch);
#pragma unroll
    for (int j = 0; j < 8; ++j) h[j] = (float)a8[j] * h[j] + (float)xs8[j];
    float* op = out + m * D_DIM + ch;
    *(f32x4*)op = *(f32x4*)h;
    *(f32x4*)(op + 4) = *(f32x4*)(h + 4);
  }
}

extern "C" void kernel_launch(void* const* d_in, const int* in_sizes, int n_in,
                              void* d_out, int out_size, void* d_ws, size_t ws_size,
                              hipStream_t stream) {
  const float* x = (const float*)d_in[0];
  const float* Wg = (const float*)d_in[1];
  const float* bg = (const float*)d_in[2];
  const float* Wv = (const float*)d_in[3];
  const float* bv = (const float*)d_in[4];
  const float* Wd = (const float*)d_in[5];
  const float* bd = (const float*)d_in[6];
  float* out = (float*)d_out;

  // workspace layout (~114.5 MiB). SP/SH get fresh space (gemm writes them
  // while other blocks still read Ah, so no overlay).
  char* ws = (char*)d_ws;
  f16* Ah = (f16*)(ws);                     // 33,554,432 B
  f16* Bh = (f16*)(ws + 33554432);          // 6,291,456 B (interleaved weights)
  f16* xsA = (f16*)(ws + 39845888);         // 33,554,432 B
  f16* aA = (f16*)(ws + 73400320);          // 33,554,432 B
  float* P = (float*)(ws + 106954752);      // NCHUNK*1024*4 = 4,194,304 B
  float* H = (float*)(ws + 111149056);      // 4,194,304 B
  float* carry = (float*)(ws + 115343360);  // 4,194,304 B
  float* SP = (float*)(ws + 119537664);     // 262,144 B
  float* SH = (float*)(ws + 119799808);     // 262,144 B  (end 120,061,952)

  cvt_all_kernel<<<9728, 256, 0, stream>>>(x, Wg, Wv, Wd, Ah, Bh);
  gemm_fused_kernel<<<1024, 512, 0, stream>>>(Ah, Bh, bg, bv, bd, xsA, aA, P, H, SP, SH);
  scan2bc_kernel<<<256, 256, 0, stream>>>(P, H, SP, SH, carry);
  scan3_kernel<<<512, 256, 0, stream>>>(xsA, aA, carry, out);
}

// Round 6
// 294.326 us; speedup vs baseline: 1.0085x; 1.0085x over previous
//
#include <hip/hip_runtime.h>
#include <cstddef>
#include <cstdint>

// MinGRU: g/v/d = x@W{g,v,d}^T + b; xs = sigmoid(g)*tanh(v); a = 0.001+0.998*sigmoid(d)
// h_t = a_t*h_{t-1} + xs_t (causal scan over S). Output h [B,S,D] f32.
// B=4, S=4096, D=1024.
// R10: (a) counted-vmcnt double-buffered K-loop (T4): per tile
//      [vmcnt(7)][s_barrier][frags+MFMA w/ setprio][s_barrier][stage t+2];
//      raw s_barrier (no full drain) replaces __syncthreads; vmcnt never 0 in
//      the main loop. R9's syncthreads drained all 7 in-flight loads per tile
//      at 1 block/CU lockstep -> 84k cy/block vs ~40k ideal.
//      (b) scan2a folded into gemm epilogue: each block's 256 rows = exactly
//      one scan segment; fold 16 chunk (p,h) in LDS, write SP/SH directly
//      (same arithmetic order -> bitwise-identical). One fewer kernel.
//      (c) scan3 unroll 2->4.
// Pipeline: cvt -> gemm_fused -> scan2bc -> scan3.

typedef _Float16 f16;
typedef f16 f16x8 __attribute__((ext_vector_type(8)));
typedef float f32x4 __attribute__((ext_vector_type(4)));

#define S_LEN 4096
#define D_DIM 1024
#define B_DIM 4
#define M_TOT (B_DIM * S_LEN)  // 16384
#define N_TOT (3 * D_DIM)      // 3072
#define K_TOT D_DIM            // 1024

#define CLEN 16
#define CPB (S_LEN / CLEN)   // 256 chunks per batch
#define NCHUNK (B_DIM * CPB) // 1024 total chunks

#define SEG 16               // chunks per scan segment
#define NSEG (CPB / SEG)     // 16 segments per batch

// ---------------- merged f32 -> f16 convert: x, then interleaved weights ----------------
__device__ __forceinline__ void cvt8(const float* s, f16* d) {
  f32x4 a = *(const f32x4*)s;
  f32x4 b = *(const f32x4*)(s + 4);
  f16x8 o;
  o[0] = (f16)a[0]; o[1] = (f16)a[1]; o[2] = (f16)a[2]; o[3] = (f16)a[3];
  o[4] = (f16)b[0]; o[5] = (f16)b[1]; o[6] = (f16)b[2]; o[7] = (f16)b[3];
  *(f16x8*)d = o;
}

__global__ void cvt_all_kernel(const float* __restrict__ x, const float* __restrict__ w0,
                               const float* __restrict__ w1, const float* __restrict__ w2,
                               f16* __restrict__ Ah, f16* __restrict__ Bh) {
  int i = (blockIdx.x * 256 + threadIdx.x) * 8;
  if (i < M_TOT * K_TOT) {
    cvt8(x + i, Ah + i);
  } else {
    int w = i - M_TOT * K_TOT;   // 0 .. 3*2^20
    int row = w >> 10;           // interleaved dst row 0..3071
    int col = w & 1023;
    int srow = row / 3;
    int mat = row - srow * 3;
    const float* s = (mat == 0) ? w0 : (mat == 1) ? w1 : w2;
    cvt8(s + srow * 1024 + col, Bh + w);
  }
}

// ---------------- fused GEMM + activation + chunk/segment scan ----------------
#define BM 256
#define BN 192
#define BK 64
#define RAWP 200  // raw g/v/d tile pitch (halves), 128-row half-pass
#define XSP 72    // xs/a tile pitch (halves), padded vs bank conflicts

// LDS layout (halves):
//   As buf0 [0,16384)  buf1 [16384,32768)     (256 rows x 64)
//   Bs buf0 [32768,45056) buf1 [45056,57344)  (192 rows x 64)
// epilogue overlay: Raw [0,25600) = 128x200, xsL [25600,34816) = 128x72,
//   aL [34816,44032) = 128x72, segP/segH f32 [44032,48128) = 2x1024 f32.
#define AS_OFF 0
#define BS_OFF 32768
#define ABUF 16384
#define BBUF 12288
#define SMEM_H 57344  // 114688 B

__device__ __forceinline__ void gl_lds16(const void* g, void* l) {
  __builtin_amdgcn_global_load_lds((const __attribute__((address_space(1))) void*)g,
                                   (__attribute__((address_space(3))) void*)l, 16, 0, 0);
}

__device__ __forceinline__ void act(float g, float v, float d, f16& xh, f16& ah) {
  float sg = 1.f / (1.f + __expf(-g));
  float tv = 1.f - 2.f / (__expf(2.f * v) + 1.f);
  float sd = 1.f / (1.f + __expf(-d));
  xh = (f16)(sg * tv);
  ah = (f16)(0.001f + 0.998f * sd);
}

// grid = 1024 blocks (XCD-swizzled to 16 N x 64 M), 512 threads = 8 waves.
__global__ __launch_bounds__(512, 2) void gemm_fused_kernel(
    const f16* __restrict__ A, const f16* __restrict__ Bt,
    const float* __restrict__ bg, const float* __restrict__ bv,
    const float* __restrict__ bd,
    f16* __restrict__ xsA, f16* __restrict__ aA,
    float* __restrict__ P, float* __restrict__ H,
    float* __restrict__ SP, float* __restrict__ SH) {
  __shared__ __attribute__((aligned(16))) f16 smem[SMEM_H];
  const int tid = threadIdx.x;
  const int lane = tid & 63;
  const int wave = tid >> 6;

  // bijective XCD swizzle (nwg=1024 % 8 == 0): XCD c owns 128 consecutive
  // orig ids = 8 M-panels x 16 N-blocks, N-major -> A panel stays L2-hot.
  const int wg = blockIdx.x;
  const int orig = (wg & 7) * 128 + (wg >> 3);
  const int bx = orig & 15;   // N block 0..15
  const int by = orig >> 4;   // M block 0..63
  const int m0 = by * BM;
  const int bn0 = bx * BN;    // interleaved B row base (multiple of 3)

  // epilogue identifiers + bias loads issued EARLY (before the K-loop) so the
  // counted vmcnt in the loop only tracks the 7 staging loads per tile.
  const int d = tid & 63;        // channel within block (64 channels)
  const int cc = tid >> 6;       // chunk 0..7 within half-pass
  const int gd = (bx << 6) + d;  // global channel
  const float Bg = bg[gd], Bv = bv[gd], Bd_ = bd[gd];

  // ---- staging addressing: round = 512 threads x 16B = 64 rows x 8 slots ----
  // LDS dest is linear (gl_lds requirement); the global SOURCE k-slot is
  // pre-swizzled: LDS[row][s] holds global slot s ^ (row&7)  (involution).
  const int srow = tid >> 3;                        // 0..63
  const int sslot = (tid & 7) ^ (srow & 7);         // swizzled source slot
  const f16* aSrc = A + (size_t)(m0 + srow) * K_TOT + sslot * 8;
  const f16* bSrc = Bt + (size_t)(bn0 + srow) * K_TOT + sslot * 8;
  f16* aDst0 = smem + AS_OFF + tid * 8;             // + buf*ABUF + r*4096
  f16* bDst0 = smem + BS_OFF + tid * 8;             // + buf*BBUF + r*4096

  // ---- fragment addressing ----
  const int wm = (wave >> 1) * 64;  // 0/64/128/192
  const int wn = (wave & 1) * 96;   // 0/96
  const int lm = lane & 15;
  const int q = lane >> 4;
  // read-side swizzle: logical slot (kk*4+q) lives at (kk*4+q)^(row&7);
  // row&7 == lm&7 for all fragment rows (wm, i*16, j*16 are 0 mod 8).
  const int sw0 = ((0 * 4 + q) ^ (lm & 7)) * 8;
  const int sw1 = ((1 * 4 + q) ^ (lm & 7)) * 8;

  f32x4 acc[4][6] = {};

  // stage(tile, buf): 7 gl_lds16 per thread (4 A + 3 B).
  auto STAGE = [&](int tile, int buf) {
    const size_t k0 = (size_t)tile * BK;
#pragma unroll
    for (int r = 0; r < 4; ++r)
      gl_lds16(aSrc + (size_t)r * 64 * K_TOT + k0, aDst0 + buf * ABUF + r * 4096);
#pragma unroll
    for (int r = 0; r < 3; ++r)
      gl_lds16(bSrc + (size_t)r * 64 * K_TOT + k0, bDst0 + buf * BBUF + r * 4096);
  };

  // ---- prologue: both buffers in flight (14 outstanding loads/thread) ----
  STAGE(0, 0);
  STAGE(1, 1);

  // ---- main loop: counted vmcnt, raw barriers, never drain to 0 until tail.
  // iter t: [vmcnt(7): tile t landed (t+1's 7 still flying)] [barrier: all
  // waves' writes visible] [frags+MFMA on buf t&1] [barrier: everyone done
  // reading buf t&1] [stage t+2 into buf t&1].
  for (int t = 0; t < 16; ++t) {
    if (t < 15) {
      asm volatile("s_waitcnt vmcnt(7)" ::: "memory");
    } else {
      asm volatile("s_waitcnt vmcnt(0)" ::: "memory");
    }
    __builtin_amdgcn_s_barrier();
    __builtin_amdgcn_sched_barrier(0);  // no ds_read hoisting above the wait

    const f16* Acur = smem + AS_OFF + (t & 1) * ABUF;
    const f16* Bcur = smem + BS_OFF + (t & 1) * BBUF;
    __builtin_amdgcn_s_setprio(1);
#pragma unroll
    for (int kk = 0; kk < 2; ++kk) {
      const int sw = kk ? sw1 : sw0;
      f16x8 af[4], bf[6];
#pragma unroll
      for (int i = 0; i < 4; ++i)
        af[i] = *(const f16x8*)&Acur[(wm + i * 16 + lm) * BK + sw];
#pragma unroll
      for (int j = 0; j < 6; ++j)
        bf[j] = *(const f16x8*)&Bcur[(wn + j * 16 + lm) * BK + sw];
#pragma unroll
      for (int i = 0; i < 4; ++i)
#pragma unroll
        for (int j = 0; j < 6; ++j)
          acc[i][j] = __builtin_amdgcn_mfma_f32_16x16x32_f16(af[i], bf[j], acc[i][j], 0, 0, 0);
    }
    __builtin_amdgcn_s_setprio(0);
    __builtin_amdgcn_sched_barrier(0);  // no ds_read sinking below barrier A

    if (t < 14) {
      __builtin_amdgcn_s_barrier();  // all waves consumed buf t&1
      STAGE(t + 2, t & 1);
    }
  }
  __syncthreads();  // full drain before epilogue overlays the staging LDS

  // ---- epilogue: two 128-row half-passes through LDS overlay ----
  f16* Raw = smem;
  f16* xsL = smem + 25600;
  f16* aLs = smem + 34816;
  float* segP = (float*)(smem + 44032);  // [16][64] chunk p per (chunk, channel)
  float* segH = segP + 1024;             // [16][64] chunk h

#pragma unroll
  for (int half = 0; half < 2; ++half) {
    // 1) raw g/v/d -> LDS tile (f16, rounding contract shared with scan3)
    if ((wave >> 2) == half) {
      const int r0 = ((wave >> 1) & 1) * 64 + ((lane >> 4) << 2);  // row in half
      const int c0 = wn + (lane & 15);
#pragma unroll
      for (int i = 0; i < 4; ++i)
#pragma unroll
        for (int j = 0; j < 6; ++j)
#pragma unroll
          for (int r = 0; r < 4; ++r)
            Raw[(r0 + i * 16 + r) * RAWP + c0 + j * 16] = (f16)acc[i][j][r];
    }
    __syncthreads();

    // 2) activation + chunk-local scan; thread = (chunk cc, channel d)
    {
      float p = 1.f, h = 0.f;
#pragma unroll
      for (int i = 0; i < CLEN; ++i) {
        const int r = cc * CLEN + i;
        const f16* t3 = &Raw[r * RAWP + 3 * d];
        f16 xh, ah;
        act((float)t3[0] + Bg, (float)t3[1] + Bv, (float)t3[2] + Bd_, xh, ah);
        xsL[r * XSP + d] = xh;
        aLs[r * XSP + d] = ah;
        // use ROUNDED values so scan3 recomposition is exactly consistent
        float xf = (float)xh, af_ = (float)ah;
        h = af_ * h + xf;
        p *= af_;
      }
      const int gs = (m0 >> 4) + half * 8 + cc;  // global chunk index = m/16
      P[(size_t)gs * D_DIM + gd] = p;
      H[(size_t)gs * D_DIM + gd] = h;
      segP[(half * 8 + cc) * 64 + d] = p;
      segH[(half * 8 + cc) * 64 + d] = h;
    }
    __syncthreads();

    // 3) coalesced xs/a global stores (2 rounds x 64 rows x 64 cols)
#pragma unroll
    for (int rr = 0; rr < 2; ++rr) {
      const int row = rr * 64 + (tid >> 3);
      const int col = (tid & 7) * 8;
      const size_t gi = (size_t)(m0 + half * 128 + row) * D_DIM + (bx << 6) + col;
      *(f16x8*)(xsA + gi) = *(const f16x8*)&xsL[row * XSP + col];
      *(f16x8*)(aA + gi) = *(const f16x8*)&aLs[row * XSP + col];
    }
    __syncthreads();  // half=1 overwrites Raw/xsL/aLs
  }

  // ---- segment aggregate (replaces scan2a): block's 256 rows = segment `by`.
  // Same fold order/arithmetic as the old scan2a -> bitwise-identical SP/SH.
  if (tid < 64) {
    float ps = 1.f, hs = 0.f;
#pragma unroll
    for (int s = 0; s < 16; ++s) {
      const float pp = segP[s * 64 + tid];
      const float hh = segH[s * 64 + tid];
      hs = pp * hs + hh;
      ps *= pp;
    }
    const size_t so = (size_t)by * D_DIM + (bx << 6) + tid;
    SP[so] = ps;
    SH[so] = hs;
  }
}

// ---------------- scan pass 2: chain segment aggregates, expand to carries ----------------
__global__ void scan2bc_kernel(const float* __restrict__ P, const float* __restrict__ H,
                               const float* __restrict__ SP, const float* __restrict__ SH,
                               float* __restrict__ carry) {
  const int u = blockIdx.x * 256 + threadIdx.x;  // 0..65535
  const int d = u & 1023;
  const int s = (u >> 10) & (NSEG - 1);  // uniform within a 256-thread block
  const int b = u >> 14;
  float h = 0.f;
  for (int s2 = 0; s2 < s; ++s2) {
    const size_t off = (size_t)(b * NSEG + s2) * D_DIM + d;
    h = SP[off] * h + SH[off];
  }
  const int gs0 = b * CPB + s * SEG;
#pragma unroll 4
  for (int c = 0; c < SEG; ++c) {
    const size_t off = (size_t)(gs0 + c) * D_DIM + d;
    carry[off] = h;
    h = P[off] * h + H[off];
  }
}

// ---------------- scan pass 3: rescan with carry, write output ----------------
__global__ void scan3_kernel(const f16* __restrict__ xsA, const f16* __restrict__ aA,
                             const float* __restrict__ carry, float* __restrict__ out) {
  const int u = blockIdx.x * 256 + threadIdx.x;
  const int cg = u & 127;
  const int b = (u >> 7) & 3;
  const int ck = u >> 9;  // 0..255
  const int ch = cg * 8;
  const int base = (b * CPB + ck) * D_DIM + ch;
  float h[8];
  *(f32x4*)h = *(const f32x4*)(carry + base);
  *(f32x4*)(h + 4) = *(const f32x4*)(carry + base + 4);
  const int t0 = ck * CLEN;
#pragma unroll 4
  for (int t = t0; t < t0 + CLEN; ++t) {
    const size_t m = (size_t)b * S_LEN + t;
    f16x8 xs8 = *(const f16x8*)(xsA + m * D_DIM + ch);
    f16x8 a8 = *(const f16x8*)(aA + m * D_DIM + ch);
#pragma unroll
    for (int j = 0; j < 8; ++j) h[j] = (float)a8[j] * h[j] + (float)xs8[j];
    float* op = out + m * D_DIM + ch;
    *(f32x4*)op = *(f32x4*)h;
    *(f32x4*)(op + 4) = *(f32x4*)(h + 4);
  }
}

extern "C" void kernel_launch(void* const* d_in, const int* in_sizes, int n_in,
                              void* d_out, int out_size, void* d_ws, size_t ws_size,
                              hipStream_t stream) {
  const float* x = (const float*)d_in[0];
  const float* Wg = (const float*)d_in[1];
  const float* bg = (const float*)d_in[2];
  const float* Wv = (const float*)d_in[3];
  const float* bv = (const float*)d_in[4];
  const float* Wd = (const float*)d_in[5];
  const float* bd = (const float*)d_in[6];
  float* out = (float*)d_out;

  // workspace layout (~114.5 MiB). SP/SH get fresh space (gemm writes them
  // while other blocks still read Ah, so no overlay).
  char* ws = (char*)d_ws;
  f16* Ah = (f16*)(ws);                     // 33,554,432 B
  f16* Bh = (f16*)(ws + 33554432);          // 6,291,456 B (interleaved weights)
  f16* xsA = (f16*)(ws + 39845888);         // 33,554,432 B
  f16* aA = (f16*)(ws + 73400320);          // 33,554,432 B
  float* P = (float*)(ws + 106954752);      // NCHUNK*1024*4 = 4,194,304 B
  float* H = (float*)(ws + 111149056);      // 4,194,304 B
  float* carry = (float*)(ws + 115343360);  // 4,194,304 B
  float* SP = (float*)(ws + 119537664);     // 262,144 B
  float* SH = (float*)(ws + 119799808);     // 262,144 B  (end 120,061,952)

  cvt_all_kernel<<<9728, 256, 0, stream>>>(x, Wg, Wv, Wd, Ah, Bh);
  gemm_fused_kernel<<<1024, 512, 0, stream>>>(Ah, Bh, bg, bv, bd, xsA, aA, P, H, SP, SH);
  scan2bc_kernel<<<256, 256, 0, stream>>>(P, H, SP, SH, carry);
  scan3_kernel<<<512, 256, 0, stream>>>(xsA, aA, carry, out);
}

// Round 7
// 285.323 us; speedup vs baseline: 1.0403x; 1.0316x over previous
//
#include <hip/hip_runtime.h>
#include <cstddef>
#include <cstdint>

// MinGRU: g/v/d = x@W{g,v,d}^T + b; xs = sigmoid(g)*tanh(v); a = 0.001+0.998*sigmoid(d)
// h_t = a_t*h_{t-1} + xs_t (causal scan over S). Output h [B,S,D] f32.
// B=4, S=4096, D=1024.
// R11: R10's regression isolated to the scheduling hints (m141: sched_barrier
//      order-pinning -42%; m190: setprio null/neg on lockstep GEMM), NOT the
//      counted-vmcnt structure. Keep counted vmcnt(7) + raw split barriers,
//      DROP all sched_barrier/setprio. Ordering stays safe: ds_reads can't
//      cross the memory-clobbered vmcnt asm; STAGE aliases the compute buffer
//      so the compiler can't hoist it over unconsumed reads; barrier handles
//      cross-wave. Also: scan2bc fused into scan3 (block-uniform ck -> uniform
//      segment chain; identical arithmetic order -> bitwise-same carry),
//      killing the carry buffer + one launch.
// Pipeline: cvt -> gemm_fused (w/ segment fold) -> scan3 (carry rebuild + out).

typedef _Float16 f16;
typedef f16 f16x8 __attribute__((ext_vector_type(8)));
typedef float f32x4 __attribute__((ext_vector_type(4)));

#define S_LEN 4096
#define D_DIM 1024
#define B_DIM 4
#define M_TOT (B_DIM * S_LEN)  // 16384
#define N_TOT (3 * D_DIM)      // 3072
#define K_TOT D_DIM            // 1024

#define CLEN 16
#define CPB (S_LEN / CLEN)   // 256 chunks per batch
#define NCHUNK (B_DIM * CPB) // 1024 total chunks

#define SEG 16               // chunks per scan segment
#define NSEG (CPB / SEG)     // 16 segments per batch

// ---------------- merged f32 -> f16 convert: x, then interleaved weights ----------------
__device__ __forceinline__ void cvt8(const float* s, f16* d) {
  f32x4 a = *(const f32x4*)s;
  f32x4 b = *(const f32x4*)(s + 4);
  f16x8 o;
  o[0] = (f16)a[0]; o[1] = (f16)a[1]; o[2] = (f16)a[2]; o[3] = (f16)a[3];
  o[4] = (f16)b[0]; o[5] = (f16)b[1]; o[6] = (f16)b[2]; o[7] = (f16)b[3];
  *(f16x8*)d = o;
}

__global__ void cvt_all_kernel(const float* __restrict__ x, const float* __restrict__ w0,
                               const float* __restrict__ w1, const float* __restrict__ w2,
                               f16* __restrict__ Ah, f16* __restrict__ Bh) {
  int i = (blockIdx.x * 256 + threadIdx.x) * 8;
  if (i < M_TOT * K_TOT) {
    cvt8(x + i, Ah + i);
  } else {
    int w = i - M_TOT * K_TOT;   // 0 .. 3*2^20
    int row = w >> 10;           // interleaved dst row 0..3071
    int col = w & 1023;
    int srow = row / 3;
    int mat = row - srow * 3;
    const float* s = (mat == 0) ? w0 : (mat == 1) ? w1 : w2;
    cvt8(s + srow * 1024 + col, Bh + w);
  }
}

// ---------------- fused GEMM + activation + chunk/segment scan ----------------
#define BM 256
#define BN 192
#define BK 64
#define RAWP 200  // raw g/v/d tile pitch (halves), 128-row half-pass
#define XSP 72    // xs/a tile pitch (halves), padded vs bank conflicts

// LDS layout (halves):
//   As buf0 [0,16384)  buf1 [16384,32768)     (256 rows x 64)
//   Bs buf0 [32768,45056) buf1 [45056,57344)  (192 rows x 64)
// epilogue overlay: Raw [0,25600) = 128x200, xsL [25600,34816) = 128x72,
//   aL [34816,44032) = 128x72, segP/segH f32 [44032,48128) = 2x1024 f32.
#define AS_OFF 0
#define BS_OFF 32768
#define ABUF 16384
#define BBUF 12288
#define SMEM_H 57344  // 114688 B

__device__ __forceinline__ void gl_lds16(const void* g, void* l) {
  __builtin_amdgcn_global_load_lds((const __attribute__((address_space(1))) void*)g,
                                   (__attribute__((address_space(3))) void*)l, 16, 0, 0);
}

__device__ __forceinline__ void act(float g, float v, float d, f16& xh, f16& ah) {
  float sg = 1.f / (1.f + __expf(-g));
  float tv = 1.f - 2.f / (__expf(2.f * v) + 1.f);
  float sd = 1.f / (1.f + __expf(-d));
  xh = (f16)(sg * tv);
  ah = (f16)(0.001f + 0.998f * sd);
}

// grid = 1024 blocks (XCD-swizzled to 16 N x 64 M), 512 threads = 8 waves.
__global__ __launch_bounds__(512, 2) void gemm_fused_kernel(
    const f16* __restrict__ A, const f16* __restrict__ Bt,
    const float* __restrict__ bg, const float* __restrict__ bv,
    const float* __restrict__ bd,
    f16* __restrict__ xsA, f16* __restrict__ aA,
    float* __restrict__ P, float* __restrict__ H,
    float* __restrict__ SP, float* __restrict__ SH) {
  __shared__ __attribute__((aligned(16))) f16 smem[SMEM_H];
  const int tid = threadIdx.x;
  const int lane = tid & 63;
  const int wave = tid >> 6;

  // bijective XCD swizzle (nwg=1024 % 8 == 0): XCD c owns 128 consecutive
  // orig ids = 8 M-panels x 16 N-blocks, N-major -> A panel stays L2-hot.
  const int wg = blockIdx.x;
  const int orig = (wg & 7) * 128 + (wg >> 3);
  const int bx = orig & 15;   // N block 0..15
  const int by = orig >> 4;   // M block 0..63
  const int m0 = by * BM;
  const int bn0 = bx * BN;    // interleaved B row base (multiple of 3)

  // epilogue identifiers + bias loads issued EARLY (before the K-loop): they
  // are the 3 oldest vmcnt entries and drain with the first vmcnt(7).
  const int d = tid & 63;        // channel within block (64 channels)
  const int cc = tid >> 6;       // chunk 0..7 within half-pass
  const int gd = (bx << 6) + d;  // global channel
  const float Bg = bg[gd], Bv = bv[gd], Bd_ = bd[gd];

  // ---- staging addressing: round = 512 threads x 16B = 64 rows x 8 slots ----
  // LDS dest is linear (gl_lds requirement); the global SOURCE k-slot is
  // pre-swizzled: LDS[row][s] holds global slot s ^ (row&7)  (involution).
  const int srow = tid >> 3;                        // 0..63
  const int sslot = (tid & 7) ^ (srow & 7);         // swizzled source slot
  const f16* aSrc = A + (size_t)(m0 + srow) * K_TOT + sslot * 8;
  const f16* bSrc = Bt + (size_t)(bn0 + srow) * K_TOT + sslot * 8;
  f16* aDst0 = smem + AS_OFF + tid * 8;             // + buf*ABUF + r*4096
  f16* bDst0 = smem + BS_OFF + tid * 8;             // + buf*BBUF + r*4096

  // ---- fragment addressing ----
  const int wm = (wave >> 1) * 64;  // 0/64/128/192
  const int wn = (wave & 1) * 96;   // 0/96
  const int lm = lane & 15;
  const int q = lane >> 4;
  // read-side swizzle: logical slot (kk*4+q) lives at (kk*4+q)^(row&7);
  // row&7 == lm&7 for all fragment rows (wm, i*16, j*16 are 0 mod 8).
  const int sw0 = ((0 * 4 + q) ^ (lm & 7)) * 8;
  const int sw1 = ((1 * 4 + q) ^ (lm & 7)) * 8;

  f32x4 acc[4][6] = {};

  // stage(tile, buf): 7 gl_lds16 per thread (4 A + 3 B).
  auto STAGE = [&](int tile, int buf) {
    const size_t k0 = (size_t)tile * BK;
#pragma unroll
    for (int r = 0; r < 4; ++r)
      gl_lds16(aSrc + (size_t)r * 64 * K_TOT + k0, aDst0 + buf * ABUF + r * 4096);
#pragma unroll
    for (int r = 0; r < 3; ++r)
      gl_lds16(bSrc + (size_t)r * 64 * K_TOT + k0, bDst0 + buf * BBUF + r * 4096);
  };

  // ---- prologue: both buffers in flight (14 staging loads/thread) ----
  STAGE(0, 0);
  STAGE(1, 1);

  // ---- main loop: counted vmcnt, raw barriers, NO scheduling hints.
  // iter t: [vmcnt(7): tile t landed, t+1's 7 still flying] [barrier: all
  // waves' stage writes visible] [frags+MFMA on buf t&1, compiler-scheduled]
  // [barrier: all waves done reading buf t&1] [stage t+2 into buf t&1].
  for (int t = 0; t < 16; ++t) {
    if (t < 15) {
      asm volatile("s_waitcnt vmcnt(7)" ::: "memory");
    } else {
      asm volatile("s_waitcnt vmcnt(0)" ::: "memory");
    }
    __builtin_amdgcn_s_barrier();

    const f16* Acur = smem + AS_OFF + (t & 1) * ABUF;
    const f16* Bcur = smem + BS_OFF + (t & 1) * BBUF;
#pragma unroll
    for (int kk = 0; kk < 2; ++kk) {
      const int sw = kk ? sw1 : sw0;
      f16x8 af[4], bf[6];
#pragma unroll
      for (int i = 0; i < 4; ++i)
        af[i] = *(const f16x8*)&Acur[(wm + i * 16 + lm) * BK + sw];
#pragma unroll
      for (int j = 0; j < 6; ++j)
        bf[j] = *(const f16x8*)&Bcur[(wn + j * 16 + lm) * BK + sw];
#pragma unroll
      for (int i = 0; i < 4; ++i)
#pragma unroll
        for (int j = 0; j < 6; ++j)
          acc[i][j] = __builtin_amdgcn_mfma_f32_16x16x32_f16(af[i], bf[j], acc[i][j], 0, 0, 0);
    }

    if (t < 14) {
      __builtin_amdgcn_s_barrier();  // all waves consumed buf t&1
      STAGE(t + 2, t & 1);
    }
  }
  __syncthreads();  // full drain before epilogue overlays the staging LDS

  // ---- epilogue: two 128-row half-passes through LDS overlay ----
  f16* Raw = smem;
  f16* xsL = smem + 25600;
  f16* aLs = smem + 34816;
  float* segP = (float*)(smem + 44032);  // [16][64] chunk p per (chunk, channel)
  float* segH = segP + 1024;             // [16][64] chunk h

#pragma unroll
  for (int half = 0; half < 2; ++half) {
    // 1) raw g/v/d -> LDS tile (f16, rounding contract shared with scan3)
    if ((wave >> 2) == half) {
      const int r0 = ((wave >> 1) & 1) * 64 + ((lane >> 4) << 2);  // row in half
      const int c0 = wn + (lane & 15);
#pragma unroll
      for (int i = 0; i < 4; ++i)
#pragma unroll
        for (int j = 0; j < 6; ++j)
#pragma unroll
          for (int r = 0; r < 4; ++r)
            Raw[(r0 + i * 16 + r) * RAWP + c0 + j * 16] = (f16)acc[i][j][r];
    }
    __syncthreads();

    // 2) activation + chunk-local scan; thread = (chunk cc, channel d)
    {
      float p = 1.f, h = 0.f;
#pragma unroll
      for (int i = 0; i < CLEN; ++i) {
        const int r = cc * CLEN + i;
        const f16* t3 = &Raw[r * RAWP + 3 * d];
        f16 xh, ah;
        act((float)t3[0] + Bg, (float)t3[1] + Bv, (float)t3[2] + Bd_, xh, ah);
        xsL[r * XSP + d] = xh;
        aLs[r * XSP + d] = ah;
        // use ROUNDED values so scan3 recomposition is exactly consistent
        float xf = (float)xh, af_ = (float)ah;
        h = af_ * h + xf;
        p *= af_;
      }
      const int gs = (m0 >> 4) + half * 8 + cc;  // global chunk index = m/16
      P[(size_t)gs * D_DIM + gd] = p;
      H[(size_t)gs * D_DIM + gd] = h;
      segP[(half * 8 + cc) * 64 + d] = p;
      segH[(half * 8 + cc) * 64 + d] = h;
    }
    __syncthreads();

    // 3) coalesced xs/a global stores (2 rounds x 64 rows x 64 cols)
#pragma unroll
    for (int rr = 0; rr < 2; ++rr) {
      const int row = rr * 64 + (tid >> 3);
      const int col = (tid & 7) * 8;
      const size_t gi = (size_t)(m0 + half * 128 + row) * D_DIM + (bx << 6) + col;
      *(f16x8*)(xsA + gi) = *(const f16x8*)&xsL[row * XSP + col];
      *(f16x8*)(aA + gi) = *(const f16x8*)&aLs[row * XSP + col];
    }
    __syncthreads();  // half=1 overwrites Raw/xsL/aLs
  }

  // ---- segment aggregate (replaces scan2a): block's 256 rows = segment `by`.
  // Same fold order/arithmetic as the old scan2a -> bitwise-identical SP/SH.
  if (tid < 64) {
    float ps = 1.f, hs = 0.f;
#pragma unroll
    for (int s = 0; s < 16; ++s) {
      const float pp = segP[s * 64 + tid];
      const float hh = segH[s * 64 + tid];
      hs = pp * hs + hh;
      ps *= pp;
    }
    const size_t so = (size_t)by * D_DIM + (bx << 6) + tid;
    SP[so] = ps;
    SH[so] = hs;
  }
}

// ---------------- scan pass 3: rebuild carry from SP/SH + P/H, rescan, out ----------------
// Fuses old scan2bc: ck (and thus segment s, chain lengths) is block-uniform,
// so the serial chains are non-divergent. Arithmetic order matches the old
// scan2bc exactly -> identical carry values.
__global__ void scan3_kernel(const f16* __restrict__ xsA, const f16* __restrict__ aA,
                             const float* __restrict__ P, const float* __restrict__ Hc,
                             const float* __restrict__ SP, const float* __restrict__ SH,
                             float* __restrict__ out) {
  const int u = blockIdx.x * 256 + threadIdx.x;
  const int cg = u & 127;
  const int b = (u >> 7) & 3;
  const int ck = u >> 9;   // 0..255, uniform per block
  const int s = ck >> 4;   // segment index, uniform per block
  const int ch = cg * 8;

  float h[8];
#pragma unroll
  for (int j = 0; j < 8; ++j) h[j] = 0.f;

  // carry chain over preceding segment aggregates (<=15 steps, L2-resident)
  for (int s2 = 0; s2 < s; ++s2) {
    const size_t off = (size_t)(b * NSEG + s2) * D_DIM + ch;
    f32x4 sp0 = *(const f32x4*)(SP + off);
    f32x4 sp1 = *(const f32x4*)(SP + off + 4);
    f32x4 sh0 = *(const f32x4*)(SH + off);
    f32x4 sh1 = *(const f32x4*)(SH + off + 4);
#pragma unroll
    for (int j = 0; j < 4; ++j) h[j] = sp0[j] * h[j] + sh0[j];
#pragma unroll
    for (int j = 0; j < 4; ++j) h[4 + j] = sp1[j] * h[4 + j] + sh1[j];
  }
  // carry chain over preceding chunks within this segment (<=15 steps)
  for (int c = s * SEG; c < ck; ++c) {
    const size_t off = (size_t)(b * CPB + c) * D_DIM + ch;
    f32x4 p0 = *(const f32x4*)(P + off);
    f32x4 p1 = *(const f32x4*)(P + off + 4);
    f32x4 h0 = *(const f32x4*)(Hc + off);
    f32x4 h1 = *(const f32x4*)(Hc + off + 4);
#pragma unroll
    for (int j = 0; j < 4; ++j) h[j] = p0[j] * h[j] + h0[j];
#pragma unroll
    for (int j = 0; j < 4; ++j) h[4 + j] = p1[j] * h[4 + j] + h1[j];
  }

  // rescan the 16 timesteps of this chunk, write f32 output
  const int t0 = ck * CLEN;
#pragma unroll 4
  for (int t = t0; t < t0 + CLEN; ++t) {
    const size_t m = (size_t)b * S_LEN + t;
    f16x8 xs8 = *(const f16x8*)(xsA + m * D_DIM + ch);
    f16x8 a8 = *(const f16x8*)(aA + m * D_DIM + ch);
#pragma unroll
    for (int j = 0; j < 8; ++j) h[j] = (float)a8[j] * h[j] + (float)xs8[j];
    float* op = out + m * D_DIM + ch;
    *(f32x4*)op = *(f32x4*)h;
    *(f32x4*)(op + 4) = *(f32x4*)(h + 4);
  }
}

extern "C" void kernel_launch(void* const* d_in, const int* in_sizes, int n_in,
                              void* d_out, int out_size, void* d_ws, size_t ws_size,
                              hipStream_t stream) {
  const float* x = (const float*)d_in[0];
  const float* Wg = (const float*)d_in[1];
  const float* bg = (const float*)d_in[2];
  const float* Wv = (const float*)d_in[3];
  const float* bv = (const float*)d_in[4];
  const float* Wd = (const float*)d_in[5];
  const float* bd = (const float*)d_in[6];
  float* out = (float*)d_out;

  // workspace layout (~110.5 MiB). No carry buffer (scan3 rebuilds carries).
  char* ws = (char*)d_ws;
  f16* Ah = (f16*)(ws);                     // 33,554,432 B
  f16* Bh = (f16*)(ws + 33554432);          // 6,291,456 B (interleaved weights)
  f16* xsA = (f16*)(ws + 39845888);         // 33,554,432 B
  f16* aA = (f16*)(ws + 73400320);          // 33,554,432 B
  float* P = (float*)(ws + 106954752);      // NCHUNK*1024*4 = 4,194,304 B
  float* H = (float*)(ws + 111149056);      // 4,194,304 B
  float* SP = (float*)(ws + 115343360);     // 262,144 B
  float* SH = (float*)(ws + 115605504);     // 262,144 B  (end 115,867,648)

  cvt_all_kernel<<<9728, 256, 0, stream>>>(x, Wg, Wv, Wd, Ah, Bh);
  gemm_fused_kernel<<<1024, 512, 0, stream>>>(Ah, Bh, bg, bv, bd, xsA, aA, P, H, SP, SH);
  scan3_kernel<<<512, 256, 0, stream>>>(xsA, aA, P, H, SP, SH, out);
}